// Round 2
// baseline (459.831 us; speedup 1.0000x reference)
//
#include <hip/hip_runtime.h>

typedef unsigned short u16;
typedef __bf16 bf16x8 __attribute__((ext_vector_type(8)));
typedef float f32x4 __attribute__((ext_vector_type(4)));

__device__ __forceinline__ float bf2f(u16 u) {
  return __builtin_bit_cast(float, (unsigned)u << 16);
}
__device__ __forceinline__ u16 f2bf(float f) {
  unsigned u = __builtin_bit_cast(unsigned, f);
  u += 0x7FFFu + ((u >> 16) & 1u);   // RNE
  return (u16)(u >> 16);
}

__device__ __forceinline__ f32x4 mfma16(bf16x8 a, bf16x8 b, f32x4 c) {
  return __builtin_amdgcn_mfma_f32_16x16x32_bf16(a, b, c, 0, 0, 0);
}

// ---------------------------------------------------------------------------
// cast f32 -> bf16, n multiple of 1024
// ---------------------------------------------------------------------------
__global__ __launch_bounds__(256) void cast_f32_bf16(const float* __restrict__ in,
                                                     u16* __restrict__ out, int n) {
  int idx = (blockIdx.x * 256 + threadIdx.x) * 4;
  if (idx < n) {
    float4 f = *(const float4*)&in[idx];
    ushort4 o;
    o.x = f2bf(f.x); o.y = f2bf(f.y); o.z = f2bf(f.z); o.w = f2bf(f.w);
    *(ushort4*)&out[idx] = o;
  }
}

// ---------------------------------------------------------------------------
// GEMM: C[M,N] = act(A[M,K] @ Bt[N,K]^T + bias [+ res]) , bf16 A/B, fp32 acc
// 128x128 tile, BK=32, 256 threads (4 waves, each 64x64 via 4x4 MFMA 16x16x32)
// ---------------------------------------------------------------------------
#define BKP 40  // padded LDS k-stride: 80B rows, 16B aligned, ~2-way bank alias

__global__ __launch_bounds__(256) void gemm_kernel(
    const u16* __restrict__ A, const u16* __restrict__ Bt,
    const float* __restrict__ bias, const u16* __restrict__ res,
    void* __restrict__ Cout, int M, int N, int K, int relu, int f32out) {
  __shared__ alignas(16) u16 As[128 * BKP];
  __shared__ alignas(16) u16 Bs[128 * BKP];
  const int tid = threadIdx.x;
  const int wave = tid >> 6, lane = tid & 63;
  const int quad = lane >> 4, l16 = lane & 15;
  const int m0 = blockIdx.y * 128, n0 = blockIdx.x * 128;
  const int wm = (wave & 1) * 64, wn = (wave >> 1) * 64;

  f32x4 acc[4][4];
#pragma unroll
  for (int i = 0; i < 4; ++i)
#pragma unroll
    for (int j = 0; j < 4; ++j) acc[i][j] = (f32x4){0.f, 0.f, 0.f, 0.f};

  const int srow = tid >> 2;       // 0..63
  const int sc8 = (tid & 3) * 8;   // 0,8,16,24

  for (int k0 = 0; k0 < K; k0 += 32) {
    __syncthreads();
#pragma unroll
    for (int it = 0; it < 2; ++it) {
      int row = srow + it * 64;
      *(bf16x8*)&As[row * BKP + sc8] =
          *(const bf16x8*)&A[(size_t)(m0 + row) * K + k0 + sc8];
      *(bf16x8*)&Bs[row * BKP + sc8] =
          *(const bf16x8*)&Bt[(size_t)(n0 + row) * K + k0 + sc8];
    }
    __syncthreads();
    bf16x8 af[4], bfr[4];
#pragma unroll
    for (int mt = 0; mt < 4; ++mt)
      af[mt] = *(const bf16x8*)&As[(wm + mt * 16 + l16) * BKP + quad * 8];
#pragma unroll
    for (int nt = 0; nt < 4; ++nt)
      bfr[nt] = *(const bf16x8*)&Bs[(wn + nt * 16 + l16) * BKP + quad * 8];
#pragma unroll
    for (int mt = 0; mt < 4; ++mt)
#pragma unroll
      for (int nt = 0; nt < 4; ++nt)
        acc[mt][nt] = mfma16(af[mt], bfr[nt], acc[mt][nt]);
  }

#pragma unroll
  for (int nt = 0; nt < 4; ++nt) {
    int col = n0 + wn + nt * 16 + l16;
    float bv = bias[col];
#pragma unroll
    for (int mt = 0; mt < 4; ++mt) {
#pragma unroll
      for (int r = 0; r < 4; ++r) {
        int row = m0 + wm + mt * 16 + quad * 4 + r;  // D: row=quad*4+reg, col=l16
        float v = acc[mt][nt][r] + bv;
        if (res) v += bf2f(res[(size_t)row * N + col]);
        if (relu) v = fmaxf(v, 0.f);
        if (f32out)
          ((float*)Cout)[(size_t)row * N + col] = v;
        else
          ((u16*)Cout)[(size_t)row * N + col] = f2bf(v);
      }
    }
  }
}

// ---------------------------------------------------------------------------
// Flash attention (non-causal). q,k: [B,S,H,64]; vt: [B,H,64,S]; out ctx [B,S,H,64]
// Block = (64 q-rows, h, b); 4 waves x 16 q-rows. K-tiles of 64 keys.
// ---------------------------------------------------------------------------
#define SP 72  // 144B LDS row stride

__global__ __launch_bounds__(256) void attn_kernel(
    const u16* __restrict__ Q, const u16* __restrict__ Km,
    const u16* __restrict__ Vt, u16* __restrict__ O) {
  __shared__ alignas(16) u16 Ks[64 * SP];
  __shared__ alignas(16) u16 Vs[64 * SP];
  __shared__ alignas(16) u16 Ps[4 * 16 * SP];
  const int tid = threadIdx.x;
  const int wave = tid >> 6, lane = tid & 63;
  const int quad = lane >> 4, l16 = lane & 15;
  const int b = blockIdx.z, h = blockIdx.y;
  const int q0 = blockIdx.x * 64 + wave * 16;
  const float scale = 0.125f;  // 1/sqrt(64)

  bf16x8 qf[2];  // A-frag: m=l16, k=quad*8+j (+32)
  {
    const size_t qoff = ((size_t)((b * 2048 + q0 + l16) * 16 + h)) * 64;
    qf[0] = *(const bf16x8*)&Q[qoff + quad * 8];
    qf[1] = *(const bf16x8*)&Q[qoff + 32 + quad * 8];
  }

  f32x4 o[4];
#pragma unroll
  for (int nt = 0; nt < 4; ++nt) o[nt] = (f32x4){0.f, 0.f, 0.f, 0.f};
  float m_i[4], l_i[4];
#pragma unroll
  for (int r = 0; r < 4; ++r) { m_i[r] = -__builtin_inff(); l_i[r] = 0.f; }

  for (int kt = 0; kt < 2048; kt += 64) {
    __syncthreads();
#pragma unroll
    for (int it = 0; it < 2; ++it) {
      int vi = it * 256 + tid;
      int row = vi >> 3, c8 = (vi & 7) * 8;
      *(bf16x8*)&Ks[row * SP + c8] =
          *(const bf16x8*)&Km[((size_t)((b * 2048 + kt + row) * 16 + h)) * 64 + c8];
      *(bf16x8*)&Vs[row * SP + c8] =
          *(const bf16x8*)&Vt[((size_t)((b * 16 + h) * 64 + row)) * 2048 + kt + c8];
    }
    __syncthreads();

    // S = Q @ K^T : B-frag lane holds K[key=l16+16nt][d=quad*8+j+32kk]
    f32x4 s[4];
#pragma unroll
    for (int nt = 0; nt < 4; ++nt) {
      f32x4 a = (f32x4){0.f, 0.f, 0.f, 0.f};
      a = mfma16(qf[0], *(const bf16x8*)&Ks[(nt * 16 + l16) * SP + quad * 8], a);
      a = mfma16(qf[1], *(const bf16x8*)&Ks[(nt * 16 + l16) * SP + 32 + quad * 8], a);
      s[nt] = a;
    }

    // online softmax; D-layout row = quad*4+r, col = l16+16nt
#pragma unroll
    for (int r = 0; r < 4; ++r) {
      float mx = fmaxf(fmaxf(s[0][r], s[1][r]), fmaxf(s[2][r], s[3][r]));
      mx = fmaxf(mx, __shfl_xor(mx, 1));
      mx = fmaxf(mx, __shfl_xor(mx, 2));
      mx = fmaxf(mx, __shfl_xor(mx, 4));
      mx = fmaxf(mx, __shfl_xor(mx, 8));
      float mnew = fmaxf(m_i[r], mx);
      float alpha = __expf(scale * (m_i[r] - mnew));  // first tile: exp(-inf)=0
      m_i[r] = mnew;
      float rs = 0.f;
#pragma unroll
      for (int nt = 0; nt < 4; ++nt) {
        float p = __expf(scale * (s[nt][r] - mnew));
        rs += p;
        Ps[(wave * 16 + quad * 4 + r) * SP + nt * 16 + l16] = f2bf(p);
        o[nt][r] *= alpha;
      }
      rs += __shfl_xor(rs, 1);
      rs += __shfl_xor(rs, 2);
      rs += __shfl_xor(rs, 4);
      rs += __shfl_xor(rs, 8);
      l_i[r] = l_i[r] * alpha + rs;
    }

    // wave-local LDS round-trip: C-layout -> A-layout (same wave, needs waitcnt only)
    asm volatile("s_waitcnt lgkmcnt(0)" ::: "memory");

#pragma unroll
    for (int kk = 0; kk < 2; ++kk) {
      bf16x8 pa = *(const bf16x8*)&Ps[(wave * 16 + l16) * SP + kk * 32 + quad * 8];
#pragma unroll
      for (int nt = 0; nt < 4; ++nt)
        o[nt] = mfma16(
            pa, *(const bf16x8*)&Vs[(nt * 16 + l16) * SP + kk * 32 + quad * 8],
            o[nt]);
    }
  }

#pragma unroll
  for (int r = 0; r < 4; ++r) {
    float inv = 1.f / l_i[r];
    size_t base = ((size_t)((b * 2048 + q0 + quad * 4 + r) * 16 + h)) * 64;
#pragma unroll
    for (int nt = 0; nt < 4; ++nt) O[base + nt * 16 + l16] = f2bf(o[nt][r] * inv);
  }
}

// ---------------------------------------------------------------------------
// 64x64 LDS-tiled transpose with f32->bf16 cast: out[c][r] = bf16(in[r][c])
// grid (C/64, R/64)
// ---------------------------------------------------------------------------
__global__ __launch_bounds__(256) void transpose_f32_bf16(
    const float* __restrict__ in, u16* __restrict__ out, int in_rs, int out_rs) {
  __shared__ alignas(16) u16 T[64][SP];
  const int tid = threadIdx.x;
  const int r0 = blockIdx.y * 64, c0 = blockIdx.x * 64;
#pragma unroll
  for (int it = 0; it < 4; ++it) {
    int vi = it * 256 + tid;
    int i = vi >> 4, j4 = (vi & 15) * 4;
    float4 f = *(const float4*)&in[(size_t)(r0 + i) * in_rs + c0 + j4];
    T[i][j4 + 0] = f2bf(f.x);
    T[i][j4 + 1] = f2bf(f.y);
    T[i][j4 + 2] = f2bf(f.z);
    T[i][j4 + 3] = f2bf(f.w);
  }
  __syncthreads();
#pragma unroll
  for (int it = 0; it < 2; ++it) {
    int vi = it * 256 + tid;
    int i = vi >> 3, j8 = (vi & 7) * 8;
    bf16x8 v;
#pragma unroll
    for (int u = 0; u < 8; ++u) ((u16*)&v)[u] = T[j8 + u][i];
    *(bf16x8*)&out[(size_t)(c0 + i) * out_rs + r0 + j8] = v;
  }
}

// v [B,S,H,64] bf16 -> vt [B,H,64,S] bf16; grid (S/64, B*H)
__global__ __launch_bounds__(256) void transpose_v(const u16* __restrict__ v,
                                                   u16* __restrict__ vt) {
  const int bh = blockIdx.y;
  const int s0 = blockIdx.x * 64;
  const u16* in = v + (size_t)(bh >> 4) * 2097152 + (size_t)(bh & 15) * 64;
  u16* out = vt + (size_t)bh * 131072;
  __shared__ alignas(16) u16 T[64][SP];
  const int tid = threadIdx.x;
#pragma unroll
  for (int it = 0; it < 2; ++it) {
    int vi = it * 256 + tid;
    int i = vi >> 3, j8 = (vi & 7) * 8;
    *(bf16x8*)&T[i][j8] = *(const bf16x8*)&in[(size_t)(s0 + i) * 1024 + j8];
  }
  __syncthreads();
#pragma unroll
  for (int it = 0; it < 2; ++it) {
    int vi = it * 256 + tid;
    int i = vi >> 3, j8 = (vi & 7) * 8;  // i = d, j8 over s
    bf16x8 vv;
#pragma unroll
    for (int u = 0; u < 8; ++u) ((u16*)&vv)[u] = T[j8 + u][i];
    *(bf16x8*)&out[(size_t)i * 2048 + s0 + j8] = vv;
  }
}

// ---------------------------------------------------------------------------
extern "C" void kernel_launch(void* const* d_in, const int* in_sizes, int n_in,
                              void* d_out, int out_size, void* d_ws,
                              size_t ws_size, hipStream_t stream) {
  const float* x = (const float*)d_in[0];
  const float* We = (const float*)d_in[1];
  const float* be = (const float*)d_in[2];
  const float* Wq = (const float*)d_in[3];
  const float* bq = (const float*)d_in[4];
  const float* Wk = (const float*)d_in[5];
  const float* bk = (const float*)d_in[6];
  const float* Wv = (const float*)d_in[7];
  const float* bv = (const float*)d_in[8];
  const float* W0 = (const float*)d_in[9];
  const float* b0 = (const float*)d_in[10];
  const float* W1 = (const float*)d_in[11];
  const float* b1 = (const float*)d_in[12];
  const float* W2 = (const float*)d_in[13];
  const float* b2 = (const float*)d_in[14];

  u16* ws = (u16*)d_ws;
  u16* xb  = ws;                 // 4096x512 bf16 of x
  u16* Wet = xb + 2097152;       // 1024x512
  u16* Wqt = Wet + 524288;       // 1024x1024 each
  u16* Wkt = Wqt + 1048576;
  u16* Wvt = Wkt + 1048576;
  u16* W0t = Wvt + 1048576;
  u16* W1t = W0t + 1048576;
  u16* W2t = W1t + 1048576;
  u16* e   = W2t + 1048576;      // [4096,1024] each below
  u16* qb  = e + 4194304;
  u16* kb  = qb + 4194304;
  u16* vb  = kb + 4194304;
  u16* vtb = vb + 4194304;
  u16* ctx = vtb + 4194304;
  u16* mha = qb;   // reuse: q dead after attention
  u16* h1  = kb;   // reuse: k dead after attention

  // x -> bf16
  cast_f32_bf16<<<2048, 256, 0, stream>>>(x, xb, 4096 * 512);

  // weight transposes (f32 in, bf16 out) -> [N][K]
  transpose_f32_bf16<<<dim3(16, 8), 256, 0, stream>>>(We, Wet, 1024, 512);
  transpose_f32_bf16<<<dim3(16, 16), 256, 0, stream>>>(Wq, Wqt, 1024, 1024);
  transpose_f32_bf16<<<dim3(16, 16), 256, 0, stream>>>(Wk, Wkt, 1024, 1024);
  transpose_f32_bf16<<<dim3(16, 16), 256, 0, stream>>>(Wv, Wvt, 1024, 1024);
  transpose_f32_bf16<<<dim3(16, 16), 256, 0, stream>>>(W0, W0t, 1024, 1024);
  transpose_f32_bf16<<<dim3(16, 16), 256, 0, stream>>>(W1, W1t, 1024, 1024);
  transpose_f32_bf16<<<dim3(16, 16), 256, 0, stream>>>(W2, W2t, 1024, 1024);

  // e = x @ We + be
  gemm_kernel<<<dim3(8, 32), 256, 0, stream>>>(xb, Wet, be, nullptr, e, 4096, 1024, 512, 0, 0);
  // q,k,v
  gemm_kernel<<<dim3(8, 32), 256, 0, stream>>>(e, Wqt, bq, nullptr, qb, 4096, 1024, 1024, 0, 0);
  gemm_kernel<<<dim3(8, 32), 256, 0, stream>>>(e, Wkt, bk, nullptr, kb, 4096, 1024, 1024, 0, 0);
  gemm_kernel<<<dim3(8, 32), 256, 0, stream>>>(e, Wvt, bv, nullptr, vb, 4096, 1024, 1024, 0, 0);
  // v -> vt [B,H,64,S]
  transpose_v<<<dim3(32, 32), 256, 0, stream>>>(vb, vtb);
  // attention -> ctx
  attn_kernel<<<dim3(32, 16, 2), 256, 0, stream>>>(qb, kb, vtb, ctx);
  // mha = e + ctx @ W0 + b0
  gemm_kernel<<<dim3(8, 32), 256, 0, stream>>>(ctx, W0t, b0, e, mha, 4096, 1024, 1024, 0, 0);
  // h1 = relu(mha @ W1 + b1)
  gemm_kernel<<<dim3(8, 32), 256, 0, stream>>>(mha, W1t, b1, nullptr, h1, 4096, 1024, 1024, 1, 0);
  // out = mha + h1 @ W2 + b2 (f32 out)
  gemm_kernel<<<dim3(8, 32), 256, 0, stream>>>(h1, W2t, b2, mha, d_out, 4096, 1024, 1024, 0, 1);
}

// Round 3
// 330.286 us; speedup vs baseline: 1.3922x; 1.3922x over previous
//
#include <hip/hip_runtime.h>

typedef unsigned short u16;
typedef __bf16 bf16x8 __attribute__((ext_vector_type(8)));
typedef float f32x4 __attribute__((ext_vector_type(4)));

__device__ __forceinline__ float bf2f(u16 u) {
  return __builtin_bit_cast(float, (unsigned)u << 16);
}
__device__ __forceinline__ u16 f2bf(float f) {
  unsigned u = __builtin_bit_cast(unsigned, f);
  u += 0x7FFFu + ((u >> 16) & 1u);   // RNE
  return (u16)(u >> 16);
}
__device__ __forceinline__ f32x4 mfma16(bf16x8 a, bf16x8 b, f32x4 c) {
  return __builtin_amdgcn_mfma_f32_16x16x32_bf16(a, b, c, 0, 0, 0);
}
// async 16B/lane global->LDS (dest = wave-uniform base + lane*16)
__device__ __forceinline__ void async_cp16(const u16* g, u16* l) {
  __builtin_amdgcn_global_load_lds((const __attribute__((address_space(1))) void*)g,
                                   (__attribute__((address_space(3))) void*)l, 16, 0, 0);
}

// ---------------------------------------------------------------------------
__global__ __launch_bounds__(256) void cast_f32_bf16(const float* __restrict__ in,
                                                     u16* __restrict__ out, int n) {
  int idx = (blockIdx.x * 256 + threadIdx.x) * 4;
  if (idx < n) {
    float4 f = *(const float4*)&in[idx];
    ushort4 o;
    o.x = f2bf(f.x); o.y = f2bf(f.y); o.z = f2bf(f.z); o.w = f2bf(f.w);
    *(ushort4*)&out[idx] = o;
  }
}

__global__ __launch_bounds__(256) void biascat(const float* __restrict__ bq,
                                               const float* __restrict__ bk,
                                               const float* __restrict__ bv,
                                               float* __restrict__ o) {
  int i = blockIdx.x * 256 + threadIdx.x;
  if (i < 3072)
    o[i] = i < 1024 ? bq[i] : (i < 2048 ? bk[i - 1024] : bv[i - 2048]);
}

// ---------------------------------------------------------------------------
// All 7 weight transposes fused: input [R][1024] f32 -> output [1024][R] bf16.
// grid (16, 16, 7); z selects the weight (z=0: We with R=512, y<8).
// ---------------------------------------------------------------------------
#define TSP 72
__global__ __launch_bounds__(256) void transpose_weights(
    const float* __restrict__ We, const float* __restrict__ Wq,
    const float* __restrict__ Wk, const float* __restrict__ Wv,
    const float* __restrict__ W0, const float* __restrict__ W1,
    const float* __restrict__ W2, u16* Wet, u16* qkvWt, u16* W0t, u16* W1t,
    u16* W2t) {
  const int z = blockIdx.z;
  const float* in;
  u16* out;
  int out_rs = 1024;
  if (z == 0) { if (blockIdx.y >= 8) return; in = We; out = Wet; out_rs = 512; }
  else if (z == 1) { in = Wq; out = qkvWt; }
  else if (z == 2) { in = Wk; out = qkvWt + 1048576; }
  else if (z == 3) { in = Wv; out = qkvWt + 2097152; }
  else if (z == 4) { in = W0; out = W0t; }
  else if (z == 5) { in = W1; out = W1t; }
  else { in = W2; out = W2t; }
  __shared__ alignas(16) u16 T[64][TSP];
  const int tid = threadIdx.x;
  const int r0 = blockIdx.y * 64, c0 = blockIdx.x * 64;
#pragma unroll
  for (int it = 0; it < 4; ++it) {
    int vi = it * 256 + tid;
    int i = vi >> 4, j4 = (vi & 15) * 4;
    float4 f = *(const float4*)&in[(size_t)(r0 + i) * 1024 + c0 + j4];
    T[i][j4 + 0] = f2bf(f.x);
    T[i][j4 + 1] = f2bf(f.y);
    T[i][j4 + 2] = f2bf(f.z);
    T[i][j4 + 3] = f2bf(f.w);
  }
  __syncthreads();
#pragma unroll
  for (int it = 0; it < 2; ++it) {
    int vi = it * 256 + tid;
    int i = vi >> 3, j8 = (vi & 7) * 8;
    bf16x8 v;
#pragma unroll
    for (int u = 0; u < 8; ++u) ((u16*)&v)[u] = T[j8 + u][i];
    *(bf16x8*)&out[(size_t)(c0 + i) * out_rs + r0 + j8] = v;
  }
}

// ---------------------------------------------------------------------------
// GEMM m97-style: C[M,N] = act(A[M,K] @ Bt[N,K]^T + bias [+res]); TM=128 fixed.
// global_load_lds width-16 staging, unpadded LDS (64B rows), BK=32, 4 waves.
// TN=128: wave 64x64 (4x4 MFMA); TN=64: wave 64x32 (4x2 MFMA).
// ---------------------------------------------------------------------------
template <int TN>
__global__ __launch_bounds__(256, (TN == 128) ? 3 : 4) void gemm_mfma(
    const u16* __restrict__ A, const u16* __restrict__ Bt,
    const float* __restrict__ bias, const u16* __restrict__ res,
    void* __restrict__ Cout, int M, int N, int K, int relu, int f32out) {
  constexpr int NT = TN / 32;
  __shared__ alignas(16) u16 As[128 * 32];
  __shared__ alignas(16) u16 Bs[TN * 32];
  const int tid = threadIdx.x;
  const int wave = tid >> 6, lane = tid & 63;
  const int quad = lane >> 4, l16 = lane & 15;
  const int m0 = blockIdx.y * 128, n0 = blockIdx.x * TN;
  const int wm = (wave & 1) * 64, wn = (wave >> 1) * (TN / 2);

  f32x4 acc[4][NT];
#pragma unroll
  for (int i = 0; i < 4; ++i)
#pragma unroll
    for (int j = 0; j < NT; ++j) acc[i][j] = (f32x4){0.f, 0.f, 0.f, 0.f};

  // per-lane global bases: lane L covers row L/4, 16B chunk L%4 of a 64B tile row
  const u16* Ag = A + (size_t)(m0 + wave * 32 + (lane >> 2)) * K + (lane & 3) * 8;
  const u16* Bg = (TN == 128)
      ? Bt + (size_t)(n0 + wave * 32 + (lane >> 2)) * K + (lane & 3) * 8
      : Bt + (size_t)(n0 + wave * 16 + (lane >> 2)) * K + (lane & 3) * 8;
  u16* AsW = &As[wave * 32 * 32];
  u16* BsW = (TN == 128) ? &Bs[wave * 32 * 32] : &Bs[wave * 16 * 32];

  for (int k0 = 0; k0 < K; k0 += 32) {
    __syncthreads();
    async_cp16(Ag + k0, AsW);
    async_cp16(Ag + k0 + (size_t)16 * K, AsW + 16 * 32);
    async_cp16(Bg + k0, BsW);
    if (TN == 128) async_cp16(Bg + k0 + (size_t)16 * K, BsW + 16 * 32);
    __syncthreads();  // compiler drains vmcnt(0) here
    bf16x8 af[4], bfr[NT];
#pragma unroll
    for (int mt = 0; mt < 4; ++mt)
      af[mt] = *(const bf16x8*)&As[(wm + mt * 16 + l16) * 32 + quad * 8];
#pragma unroll
    for (int nt = 0; nt < NT; ++nt)
      bfr[nt] = *(const bf16x8*)&Bs[(wn + nt * 16 + l16) * 32 + quad * 8];
#pragma unroll
    for (int mt = 0; mt < 4; ++mt)
#pragma unroll
      for (int nt = 0; nt < NT; ++nt)
        acc[mt][nt] = mfma16(af[mt], bfr[nt], acc[mt][nt]);
  }

#pragma unroll
  for (int nt = 0; nt < NT; ++nt) {
    int col = n0 + wn + nt * 16 + l16;
    float bv = bias[col];
#pragma unroll
    for (int mt = 0; mt < 4; ++mt) {
#pragma unroll
      for (int r = 0; r < 4; ++r) {
        int row = m0 + wm + mt * 16 + quad * 4 + r;  // D: row=quad*4+reg, col=l16
        float v = acc[mt][nt][r] + bv;
        if (res) v += bf2f(res[(size_t)row * N + col]);
        if (relu) v = fmaxf(v, 0.f);
        if (f32out)
          ((float*)Cout)[(size_t)row * N + col] = v;
        else
          ((u16*)Cout)[(size_t)row * N + col] = f2bf(v);
      }
    }
  }
}

// ---------------------------------------------------------------------------
// Flash attention, fixed-base softmax (no running max; Q pre-scaled by 0.125,
// exact in bf16). qkv: [B,S,3072] (q|k|v); Vt: [B,H,64,S]; out ctx [B,S,1024].
// Block = 128 q-rows x (h,b); 4 waves x 32 rows. 64-key tiles.
// ---------------------------------------------------------------------------
#define SP 72
__global__ __launch_bounds__(256, 2) void attn_kernel(
    const u16* __restrict__ QKV, const u16* __restrict__ Vt,
    u16* __restrict__ O) {
  __shared__ alignas(16) u16 Ks[64 * SP];
  __shared__ alignas(16) u16 Vs[64 * SP];
  __shared__ alignas(16) u16 Ps[128 * SP];
  const int tid = threadIdx.x;
  const int wave = tid >> 6, lane = tid & 63;
  const int quad = lane >> 4, l16 = lane & 15;
  const int b = blockIdx.z, h = blockIdx.y;
  const int q0 = blockIdx.x * 128 + wave * 32;

  bf16x8 qf[2][2];  // A-frag: m=l16, k=quad*8+j (+32); pre-scaled by 1/8
#pragma unroll
  for (int mt = 0; mt < 2; ++mt) {
    const size_t qoff = (size_t)(b * 2048 + q0 + mt * 16 + l16) * 3072 + h * 64;
#pragma unroll
    for (int kk = 0; kk < 2; ++kk) {
      bf16x8 raw = *(const bf16x8*)&QKV[qoff + kk * 32 + quad * 8];
#pragma unroll
      for (int u = 0; u < 8; ++u)
        ((u16*)&raw)[u] = f2bf(0.125f * bf2f(((u16*)&raw)[u]));
      qf[mt][kk] = raw;
    }
  }

  f32x4 o[2][4];
  float lsum[2][4];
#pragma unroll
  for (int mt = 0; mt < 2; ++mt)
#pragma unroll
    for (int nt = 0; nt < 4; ++nt) o[mt][nt] = (f32x4){0.f, 0.f, 0.f, 0.f};
#pragma unroll
  for (int mt = 0; mt < 2; ++mt)
#pragma unroll
    for (int r = 0; r < 4; ++r) lsum[mt][r] = 0.f;

  for (int kt = 0; kt < 2048; kt += 64) {
    __syncthreads();
#pragma unroll
    for (int it = 0; it < 2; ++it) {
      int vi = it * 256 + tid;
      int row = vi >> 3, c8 = (vi & 7) * 8;
      *(bf16x8*)&Ks[row * SP + c8] = *(const bf16x8*)&QKV[
          (size_t)(b * 2048 + kt + row) * 3072 + 1024 + h * 64 + c8];
      *(bf16x8*)&Vs[row * SP + c8] = *(const bf16x8*)&Vt[
          (size_t)((b * 16 + h) * 64 + row) * 2048 + kt + c8];
    }
    __syncthreads();

    // S = (Q/8) @ K^T
    f32x4 s[2][4];
#pragma unroll
    for (int nt = 0; nt < 4; ++nt) {
      bf16x8 k0f = *(const bf16x8*)&Ks[(nt * 16 + l16) * SP + quad * 8];
      bf16x8 k1f = *(const bf16x8*)&Ks[(nt * 16 + l16) * SP + 32 + quad * 8];
#pragma unroll
      for (int mt = 0; mt < 2; ++mt) {
        f32x4 a = (f32x4){0.f, 0.f, 0.f, 0.f};
        a = mfma16(qf[mt][0], k0f, a);
        a = mfma16(qf[mt][1], k1f, a);
        s[mt][nt] = a;
      }
    }

    // fixed-base softmax numerator; per-lane l accumulation (no shuffles here)
#pragma unroll
    for (int mt = 0; mt < 2; ++mt)
#pragma unroll
      for (int r = 0; r < 4; ++r) {
        int prow = wave * 32 + mt * 16 + quad * 4 + r;
#pragma unroll
        for (int nt = 0; nt < 4; ++nt) {
          float p = __expf(s[mt][nt][r]);
          lsum[mt][r] += p;
          Ps[prow * SP + nt * 16 + l16] = f2bf(p);
        }
      }

    // wave-local C-layout -> A-layout round-trip (own rows only)
    asm volatile("s_waitcnt lgkmcnt(0)" ::: "memory");

#pragma unroll
    for (int kk = 0; kk < 2; ++kk) {
      bf16x8 pa0 = *(const bf16x8*)&Ps[(wave * 32 + l16) * SP + kk * 32 + quad * 8];
      bf16x8 pa1 = *(const bf16x8*)&Ps[(wave * 32 + 16 + l16) * SP + kk * 32 + quad * 8];
#pragma unroll
      for (int nt = 0; nt < 4; ++nt) {
        bf16x8 vb = *(const bf16x8*)&Vs[(nt * 16 + l16) * SP + kk * 32 + quad * 8];
        o[0][nt] = mfma16(pa0, vb, o[0][nt]);
        o[1][nt] = mfma16(pa1, vb, o[1][nt]);
      }
    }
  }

#pragma unroll
  for (int mt = 0; mt < 2; ++mt)
#pragma unroll
    for (int r = 0; r < 4; ++r) {
      float l = lsum[mt][r];
      l += __shfl_xor(l, 1);
      l += __shfl_xor(l, 2);
      l += __shfl_xor(l, 4);
      l += __shfl_xor(l, 8);
      float inv = 1.f / l;
      size_t base = (size_t)(b * 2048 + q0 + mt * 16 + quad * 4 + r) * 1024 + h * 64;
#pragma unroll
      for (int nt = 0; nt < 4; ++nt)
        O[base + nt * 16 + l16] = f2bf(o[mt][nt][r] * inv);
    }
}

// v slice of qkv [B,S,3072] -> vt [B,H,64,S]; grid (S/64, B*H)
__global__ __launch_bounds__(256) void transpose_v(const u16* __restrict__ QKV,
                                                   u16* __restrict__ vt) {
  const int bh = blockIdx.y;
  const int b = bh >> 4, h = bh & 15;
  const int s0 = blockIdx.x * 64;
  const u16* in = QKV + (size_t)b * 2048 * 3072 + 2048 + h * 64;
  u16* out = vt + (size_t)bh * 131072;
  __shared__ alignas(16) u16 T[64][TSP];
  const int tid = threadIdx.x;
#pragma unroll
  for (int it = 0; it < 2; ++it) {
    int vi = it * 256 + tid;
    int i = vi >> 3, j8 = (vi & 7) * 8;
    *(bf16x8*)&T[i][j8] = *(const bf16x8*)&in[(size_t)(s0 + i) * 3072 + j8];
  }
  __syncthreads();
#pragma unroll
  for (int it = 0; it < 2; ++it) {
    int vi = it * 256 + tid;
    int i = vi >> 3, j8 = (vi & 7) * 8;  // i = d, j8 over s
    bf16x8 vv;
#pragma unroll
    for (int u = 0; u < 8; ++u) ((u16*)&vv)[u] = T[j8 + u][i];
    *(bf16x8*)&out[(size_t)i * 2048 + s0 + j8] = vv;
  }
}

// ---------------------------------------------------------------------------
extern "C" void kernel_launch(void* const* d_in, const int* in_sizes, int n_in,
                              void* d_out, int out_size, void* d_ws,
                              size_t ws_size, hipStream_t stream) {
  const float* x = (const float*)d_in[0];
  const float* We = (const float*)d_in[1];
  const float* be = (const float*)d_in[2];
  const float* Wq = (const float*)d_in[3];
  const float* bq = (const float*)d_in[4];
  const float* Wk = (const float*)d_in[5];
  const float* bk = (const float*)d_in[6];
  const float* Wv = (const float*)d_in[7];
  const float* bv = (const float*)d_in[8];
  const float* W0 = (const float*)d_in[9];
  const float* b0 = (const float*)d_in[10];
  const float* W1 = (const float*)d_in[11];
  const float* b1 = (const float*)d_in[12];
  const float* W2 = (const float*)d_in[13];
  const float* b2 = (const float*)d_in[14];

  u16* ws = (u16*)d_ws;
  // region A (reused): xb+Wet+qkvWt live until qkv-gemm; ctx aliases it after
  u16* xb = ws;                         // 2,097,152
  u16* Wet = xb + 2097152;              //   524,288
  u16* qkvWt = Wet + 524288;            // 3,145,728
  u16* ctx = ws;                        // alias (4,194,304 <= 5,767,168) after qkv-gemm
  u16* W0t = qkvWt + 3145728;           // 1,048,576 each
  u16* W1t = W0t + 1048576;
  u16* W2t = W1t + 1048576;
  float* biasqkv = (float*)(W2t + 1048576);  // 3072 f32 = 6144 u16
  u16* e = W2t + 1048576 + 6144;        // 4,194,304
  u16* qkv = e + 4194304;               // 12,582,912
  u16* vtb = qkv + 12582912;            // 4,194,304
  u16* mha = qkv;                       // alias: qkv dead after attn
  u16* h1 = e;                          // alias: e dead after W0-gemm

  cast_f32_bf16<<<2048, 256, 0, stream>>>(x, xb, 4096 * 512);
  transpose_weights<<<dim3(16, 16, 7), 256, 0, stream>>>(
      We, Wq, Wk, Wv, W0, W1, W2, Wet, qkvWt, W0t, W1t, W2t);
  biascat<<<12, 256, 0, stream>>>(bq, bk, bv, biasqkv);

  // e = x @ We + be
  gemm_mfma<64><<<dim3(16, 32), 256, 0, stream>>>(xb, Wet, be, nullptr, e,
                                                  4096, 1024, 512, 0, 0);
  // qkv = e @ [Wq|Wk|Wv] + [bq|bk|bv]
  gemm_mfma<128><<<dim3(24, 32), 256, 0, stream>>>(e, qkvWt, biasqkv, nullptr,
                                                   qkv, 4096, 3072, 1024, 0, 0);
  transpose_v<<<dim3(32, 32), 256, 0, stream>>>(qkv, vtb);
  attn_kernel<<<dim3(16, 16, 2), 256, 0, stream>>>(qkv, vtb, ctx);
  // mha = e + ctx @ W0 + b0
  gemm_mfma<64><<<dim3(16, 32), 256, 0, stream>>>(ctx, W0t, b0, e, mha, 4096,
                                                  1024, 1024, 0, 0);
  // h1 = relu(mha @ W1 + b1)
  gemm_mfma<64><<<dim3(16, 32), 256, 0, stream>>>(mha, W1t, b1, nullptr, h1,
                                                  4096, 1024, 1024, 1, 0);
  // out = mha + h1 @ W2 + b2 (f32)
  gemm_mfma<64><<<dim3(16, 32), 256, 0, stream>>>(h1, W2t, b2, mha, d_out,
                                                  4096, 1024, 1024, 0, 1);
}

// Round 4
// 291.174 us; speedup vs baseline: 1.5792x; 1.1343x over previous
//
#include <hip/hip_runtime.h>

typedef unsigned short u16;
typedef __bf16 bf16x8 __attribute__((ext_vector_type(8)));
typedef float f32x4 __attribute__((ext_vector_type(4)));

__device__ __forceinline__ float bf2f(u16 u) {
  return __builtin_bit_cast(float, (unsigned)u << 16);
}
__device__ __forceinline__ u16 f2bf(float f) {
  unsigned u = __builtin_bit_cast(unsigned, f);
  u += 0x7FFFu + ((u >> 16) & 1u);  // RNE
  return (u16)(u >> 16);
}
__device__ __forceinline__ unsigned pk2(float a, float b) {
  return (unsigned)f2bf(a) | ((unsigned)f2bf(b) << 16);
}
__device__ __forceinline__ f32x4 mfma16(bf16x8 a, bf16x8 b, f32x4 c) {
  return __builtin_amdgcn_mfma_f32_16x16x32_bf16(a, b, c, 0, 0, 0);
}
// async 16B/lane global->LDS; LDS dest = wave-uniform base + lane*16
__device__ __forceinline__ void async_cp16(const u16* g, u16* l) {
  __builtin_amdgcn_global_load_lds((const __attribute__((address_space(1))) void*)g,
                                   (__attribute__((address_space(3))) void*)l, 16, 0, 0);
}
#define S_BARRIER() asm volatile("s_barrier" ::: "memory")

// ---------------------------------------------------------------------------
__global__ __launch_bounds__(256) void cast_f32_bf16(const float* __restrict__ in,
                                                     u16* __restrict__ out, int n) {
  int idx = (blockIdx.x * 256 + threadIdx.x) * 4;
  if (idx < n) {
    float4 f = *(const float4*)&in[idx];
    ushort4 o;
    o.x = f2bf(f.x); o.y = f2bf(f.y); o.z = f2bf(f.z); o.w = f2bf(f.w);
    *(ushort4*)&out[idx] = o;
  }
}

__global__ __launch_bounds__(256) void biascat(const float* __restrict__ bq,
                                               const float* __restrict__ bk,
                                               const float* __restrict__ bv,
                                               float* __restrict__ o) {
  int i = blockIdx.x * 256 + threadIdx.x;
  if (i < 3072)
    o[i] = i < 1024 ? bq[i] : (i < 2048 ? bk[i - 1024] : bv[i - 2048]);
}

// ---------------------------------------------------------------------------
// 7 weight transposes fused: [R][1024] f32 -> [1024][R] bf16. grid (16,16,7).
// ---------------------------------------------------------------------------
#define TSP 72
__global__ __launch_bounds__(256) void transpose_weights(
    const float* __restrict__ We, const float* __restrict__ Wq,
    const float* __restrict__ Wk, const float* __restrict__ Wv,
    const float* __restrict__ W0, const float* __restrict__ W1,
    const float* __restrict__ W2, u16* Wet, u16* qkvWt, u16* W0t, u16* W1t,
    u16* W2t) {
  const int z = blockIdx.z;
  const float* in;
  u16* out;
  int out_rs = 1024;
  if (z == 0) { if (blockIdx.y >= 8) return; in = We; out = Wet; out_rs = 512; }
  else if (z == 1) { in = Wq; out = qkvWt; }
  else if (z == 2) { in = Wk; out = qkvWt + 1048576; }
  else if (z == 3) { in = Wv; out = qkvWt + 2097152; }
  else if (z == 4) { in = W0; out = W0t; }
  else if (z == 5) { in = W1; out = W1t; }
  else { in = W2; out = W2t; }
  __shared__ alignas(16) u16 T[64][TSP];
  const int tid = threadIdx.x;
  const int r0 = blockIdx.y * 64, c0 = blockIdx.x * 64;
#pragma unroll
  for (int it = 0; it < 4; ++it) {
    int vi = it * 256 + tid;
    int i = vi >> 4, j4 = (vi & 15) * 4;
    float4 f = *(const float4*)&in[(size_t)(r0 + i) * 1024 + c0 + j4];
    T[i][j4 + 0] = f2bf(f.x);
    T[i][j4 + 1] = f2bf(f.y);
    T[i][j4 + 2] = f2bf(f.z);
    T[i][j4 + 3] = f2bf(f.w);
  }
  __syncthreads();
#pragma unroll
  for (int it = 0; it < 2; ++it) {
    int vi = it * 256 + tid;
    int i = vi >> 3, j8 = (vi & 7) * 8;
    bf16x8 v;
#pragma unroll
    for (int u = 0; u < 8; ++u) ((u16*)&v)[u] = T[j8 + u][i];
    *(bf16x8*)&out[(size_t)(c0 + i) * out_rs + r0 + j8] = v;
  }
}

// ---------------------------------------------------------------------------
// GEMM: C[M,N] = act(A @ Bt^T + bias [+res]). TM=128, TN=64, BK=64.
// Async double-buffered global_load_lds staging, raw-barrier K-loop,
// XOR-swizzled 128B LDS rows. 4 waves, each 64x32 (4x2 MFMA).
// ---------------------------------------------------------------------------
__global__ __launch_bounds__(256, 3) void gemm_mfma(
    const u16* __restrict__ A, const u16* __restrict__ Bt,
    const float* __restrict__ bias, const u16* __restrict__ res,
    void* __restrict__ Cout, int M, int N, int K, int relu, int f32out) {
  __shared__ alignas(16) u16 As[2][128 * 64];
  __shared__ alignas(16) u16 Bs[2][64 * 64];
  const int tid = threadIdx.x;
  const int wave = tid >> 6, lane = tid & 63;
  const int quad = lane >> 4, l16 = lane & 15;
  const int m0 = blockIdx.y * 128, n0 = blockIdx.x * 64;
  const int wm = (wave & 1) * 64, wn = (wave >> 1) * 32;

  f32x4 acc[4][2];
#pragma unroll
  for (int i = 0; i < 4; ++i)
#pragma unroll
    for (int j = 0; j < 2; ++j) acc[i][j] = (f32x4){0.f, 0.f, 0.f, 0.f};

  // staging: lane covers row srow=lane>>3 (of 8), LDS chunk lane&7; the global
  // chunk is XOR-swizzled by row so LDS[r][c] = G[r][c ^ (r&7)]
  const int srow = lane >> 3;
  const int schunk = (lane & 7) ^ (srow & 7);
  const u16* Ag = A + (size_t)(m0 + wave * 32 + srow) * K + schunk * 8;
  const u16* Bg = Bt + (size_t)(n0 + wave * 16 + srow) * K + schunk * 8;
  u16* AsW0 = &As[0][(wave * 32) * 64];
  u16* BsW0 = &Bs[0][(wave * 16) * 64];
  u16* AsW1 = &As[1][(wave * 32) * 64];
  u16* BsW1 = &Bs[1][(wave * 16) * 64];

#define GEMM_ISSUE(ab, bb, k)                                   \
  {                                                             \
    _Pragma("unroll") for (int i = 0; i < 4; ++i)               \
        async_cp16(Ag + (k) + (size_t)i * 8 * K, (ab) + i * 512); \
    _Pragma("unroll") for (int i = 0; i < 2; ++i)               \
        async_cp16(Bg + (k) + (size_t)i * 8 * K, (bb) + i * 512); \
  }

  GEMM_ISSUE(AsW0, BsW0, 0);
  const int T = K >> 6;
  const int swz = (l16 & 7);
  for (int t = 0; t < T; ++t) {
    const int cb = t & 1;
    S_BARRIER();  // prior compute on buf cb^1 finished everywhere
    const int kn = (t + 1 < T) ? ((t + 1) << 6) : 0;  // wrap: harmless refetch
    if (cb == 0) GEMM_ISSUE(AsW1, BsW1, kn) else GEMM_ISSUE(AsW0, BsW0, kn);
    asm volatile("s_waitcnt vmcnt(6)" ::: "memory");  // tile-t loads landed
    S_BARRIER();
#pragma unroll
    for (int kk = 0; kk < 2; ++kk) {
      bf16x8 af[4], bfr[2];
#pragma unroll
      for (int mt = 0; mt < 4; ++mt)
        af[mt] = *(const bf16x8*)&As[cb][(wm + mt * 16 + l16) * 64 +
                                        ((kk * 4 + quad) ^ swz) * 8];
#pragma unroll
      for (int nt = 0; nt < 2; ++nt)
        bfr[nt] = *(const bf16x8*)&Bs[cb][(wn + nt * 16 + l16) * 64 +
                                          ((kk * 4 + quad) ^ swz) * 8];
#pragma unroll
      for (int mt = 0; mt < 4; ++mt)
#pragma unroll
        for (int nt = 0; nt < 2; ++nt)
          acc[mt][nt] = mfma16(af[mt], bfr[nt], acc[mt][nt]);
    }
  }
  asm volatile("s_waitcnt vmcnt(0)" ::: "memory");  // drain before LDS dealloc

#pragma unroll
  for (int nt = 0; nt < 2; ++nt) {
    int col = n0 + wn + nt * 16 + l16;
    float bv = bias[col];
#pragma unroll
    for (int mt = 0; mt < 4; ++mt) {
#pragma unroll
      for (int r = 0; r < 4; ++r) {
        int row = m0 + wm + mt * 16 + quad * 4 + r;  // D: row=quad*4+r, col=l16
        float v = acc[mt][nt][r] + bv;
        if (res) v += bf2f(res[(size_t)row * N + col]);
        if (relu) v = fmaxf(v, 0.f);
        if (f32out)
          ((float*)Cout)[(size_t)row * N + col] = v;
        else
          ((u16*)Cout)[(size_t)row * N + col] = f2bf(v);
      }
    }
  }
}

// ---------------------------------------------------------------------------
// Flash attention, transposed form: S^T = K@Q^T, ctx^T = V^T@P^T.
// Fixed-base softmax (Q pre-scaled 1/8). qkv [B,S,3072]; Vt [B,H,64,S].
// Block = 128 q-rows x (h,b); wave = 32 q-rows. 64-key tiles, dbuf staging.
// ---------------------------------------------------------------------------
__global__ __launch_bounds__(256, 2) void attn_kernel(
    const u16* __restrict__ QKV, const u16* __restrict__ Vt,
    u16* __restrict__ O) {
  __shared__ alignas(16) u16 Ks[2][64 * 64];  // [key][d], swizzled
  __shared__ alignas(16) u16 Vs[2][64 * 64];  // [d][s], swizzled
  __shared__ alignas(16) u16 Ps[4][32 * 72];  // per-wave P[qrow][key]
  const int tid = threadIdx.x;
  const int wave = tid >> 6, lane = tid & 63;
  const int quad = lane >> 4, l16 = lane & 15;
  const int b = blockIdx.z, h = blockIdx.y;
  const int q0 = blockIdx.x * 128 + wave * 32;

  // Q as B-frags (k=d=quad*8+j, n=qrow=l16), pre-scaled by 1/8 (exact)
  bf16x8 qf[2][2];
#pragma unroll
  for (int qt = 0; qt < 2; ++qt) {
    const size_t qoff = (size_t)(b * 2048 + q0 + qt * 16 + l16) * 3072 + h * 64;
#pragma unroll
    for (int kk = 0; kk < 2; ++kk) {
      bf16x8 raw = *(const bf16x8*)&QKV[qoff + kk * 32 + quad * 8];
#pragma unroll
      for (int u = 0; u < 8; ++u)
        ((u16*)&raw)[u] = f2bf(0.125f * bf2f(((u16*)&raw)[u]));
      qf[qt][kk] = raw;
    }
  }

  f32x4 o[4][2];  // ctx^T [d-tile][q-tile]
#pragma unroll
  for (int mt = 0; mt < 4; ++mt)
#pragma unroll
    for (int qt = 0; qt < 2; ++qt) o[mt][qt] = (f32x4){0.f, 0.f, 0.f, 0.f};
  float lsum[2] = {0.f, 0.f};

  const int srow = lane >> 3;
  const int schunk = (lane & 7) ^ (srow & 7);
  const u16* Kg = QKV + (size_t)(b * 2048 + wave * 16 + srow) * 3072 + 1024 +
                  h * 64 + schunk * 8;
  const u16* Vg = Vt + (size_t)((b * 16 + h) * 64 + wave * 16 + srow) * 2048 +
                  schunk * 8;
  u16* KsW0 = &Ks[0][(wave * 16) * 64];
  u16* VsW0 = &Vs[0][(wave * 16) * 64];
  u16* KsW1 = &Ks[1][(wave * 16) * 64];
  u16* VsW1 = &Vs[1][(wave * 16) * 64];

#define ATTN_ISSUE(kb, vb, kt)                                          \
  {                                                                     \
    async_cp16(Kg + (size_t)(kt) * 3072, (kb));                         \
    async_cp16(Kg + (size_t)((kt) + 8) * 3072, (kb) + 512);             \
    async_cp16(Vg + (kt), (vb));                                        \
    async_cp16(Vg + (kt) + (size_t)8 * 2048, (vb) + 512);               \
  }

  ATTN_ISSUE(KsW0, VsW0, 0);
  const int swz = (l16 & 7);
  u16* PsW = &Ps[wave][0];
  for (int t = 0; t < 32; ++t) {
    const int cb = t & 1;
    S_BARRIER();
    const int ktn = (t + 1 < 32) ? ((t + 1) * 64) : 0;
    if (cb == 0) ATTN_ISSUE(KsW1, VsW1, ktn) else ATTN_ISSUE(KsW0, VsW0, ktn);
    asm volatile("s_waitcnt vmcnt(4)" ::: "memory");
    S_BARRIER();

    // S^T = K @ Q^T : D[m=key][n=qrow]
    f32x4 st[4][2];
#pragma unroll
    for (int km = 0; km < 4; ++km)
#pragma unroll
      for (int qt = 0; qt < 2; ++qt) st[km][qt] = (f32x4){0.f, 0.f, 0.f, 0.f};
#pragma unroll
    for (int kk = 0; kk < 2; ++kk)
#pragma unroll
      for (int km = 0; km < 4; ++km) {
        bf16x8 kf = *(const bf16x8*)&Ks[cb][(km * 16 + l16) * 64 +
                                           ((kk * 4 + quad) ^ swz) * 8];
        st[km][0] = mfma16(kf, qf[0][kk], st[km][0]);
        st[km][1] = mfma16(kf, qf[1][kk], st[km][1]);
      }

    // exp + pack 4 keys -> one b64 LDS write; P[qrow][key] key-contiguous
#pragma unroll
    for (int qt = 0; qt < 2; ++qt)
#pragma unroll
      for (int km = 0; km < 4; ++km) {
        float e0 = __expf(st[km][qt][0]), e1 = __expf(st[km][qt][1]);
        float e2 = __expf(st[km][qt][2]), e3 = __expf(st[km][qt][3]);
        lsum[qt] += (e0 + e1) + (e2 + e3);
        uint2 pk;
        pk.x = pk2(e0, e1);
        pk.y = pk2(e2, e3);
        *(uint2*)&PsW[(qt * 16 + l16) * 72 + km * 16 + quad * 4] = pk;
      }
    asm volatile("s_waitcnt lgkmcnt(0)" ::: "memory");  // wave-local round-trip

    // ctx^T += V^T @ P^T
#pragma unroll
    for (int kk2 = 0; kk2 < 2; ++kk2) {
      bf16x8 pf0 = *(const bf16x8*)&PsW[l16 * 72 + kk2 * 32 + quad * 8];
      bf16x8 pf1 = *(const bf16x8*)&PsW[(16 + l16) * 72 + kk2 * 32 + quad * 8];
#pragma unroll
      for (int mt = 0; mt < 4; ++mt) {
        bf16x8 vf = *(const bf16x8*)&Vs[cb][(mt * 16 + l16) * 64 +
                                           ((kk2 * 4 + quad) ^ swz) * 8];
        o[mt][0] = mfma16(vf, pf0, o[mt][0]);
        o[mt][1] = mfma16(vf, pf1, o[mt][1]);
      }
    }
  }
  asm volatile("s_waitcnt vmcnt(0)" ::: "memory");  // drain before LDS dealloc

  // epilogue: lane holds ctx^T[d=mt*16+quad*4+r][qrow=qt*16+l16] -> packed 8B
#pragma unroll
  for (int qt = 0; qt < 2; ++qt) {
    float l = lsum[qt];
    l += __shfl_xor(l, 16);
    l += __shfl_xor(l, 32);
    float inv = 1.f / l;
    size_t base = (size_t)(b * 2048 + q0 + qt * 16 + l16) * 1024 + h * 64;
#pragma unroll
    for (int mt = 0; mt < 4; ++mt) {
      uint2 pk;
      pk.x = pk2(o[mt][qt][0] * inv, o[mt][qt][1] * inv);
      pk.y = pk2(o[mt][qt][2] * inv, o[mt][qt][3] * inv);
      *(uint2*)&O[base + mt * 16 + quad * 4] = pk;
    }
  }
}

// v slice of qkv [B,S,3072] -> vt [B,H,64,S]; grid (S/64, B*H)
__global__ __launch_bounds__(256) void transpose_v(const u16* __restrict__ QKV,
                                                   u16* __restrict__ vt) {
  const int bh = blockIdx.y;
  const int b = bh >> 4, h = bh & 15;
  const int s0 = blockIdx.x * 64;
  const u16* in = QKV + (size_t)b * 2048 * 3072 + 2048 + h * 64;
  u16* out = vt + (size_t)bh * 131072;
  __shared__ alignas(16) u16 T[64][TSP];
  const int tid = threadIdx.x;
#pragma unroll
  for (int it = 0; it < 2; ++it) {
    int vi = it * 256 + tid;
    int i = vi >> 3, j8 = (vi & 7) * 8;
    *(bf16x8*)&T[i][j8] = *(const bf16x8*)&in[(size_t)(s0 + i) * 3072 + j8];
  }
  __syncthreads();
#pragma unroll
  for (int it = 0; it < 2; ++it) {
    int vi = it * 256 + tid;
    int i = vi >> 3, j8 = (vi & 7) * 8;  // i = d, j8 over s
    bf16x8 vv;
#pragma unroll
    for (int u = 0; u < 8; ++u) ((u16*)&vv)[u] = T[j8 + u][i];
    *(bf16x8*)&out[(size_t)i * 2048 + s0 + j8] = vv;
  }
}

// ---------------------------------------------------------------------------
extern "C" void kernel_launch(void* const* d_in, const int* in_sizes, int n_in,
                              void* d_out, int out_size, void* d_ws,
                              size_t ws_size, hipStream_t stream) {
  const float* x = (const float*)d_in[0];
  const float* We = (const float*)d_in[1];
  const float* be = (const float*)d_in[2];
  const float* Wq = (const float*)d_in[3];
  const float* bq = (const float*)d_in[4];
  const float* Wk = (const float*)d_in[5];
  const float* bk = (const float*)d_in[6];
  const float* Wv = (const float*)d_in[7];
  const float* bv = (const float*)d_in[8];
  const float* W0 = (const float*)d_in[9];
  const float* b0 = (const float*)d_in[10];
  const float* W1 = (const float*)d_in[11];
  const float* b1 = (const float*)d_in[12];
  const float* W2 = (const float*)d_in[13];
  const float* b2 = (const float*)d_in[14];

  u16* ws = (u16*)d_ws;
  u16* xb = ws;                         // 2,097,152
  u16* Wet = xb + 2097152;              //   524,288
  u16* qkvWt = Wet + 524288;            // 3,145,728
  u16* ctx = ws;                        // alias after qkv-gemm
  u16* W0t = qkvWt + 3145728;
  u16* W1t = W0t + 1048576;
  u16* W2t = W1t + 1048576;
  float* biasqkv = (float*)(W2t + 1048576);  // 3072 f32
  u16* e = W2t + 1048576 + 6144;
  u16* qkv = e + 4194304;               // 12,582,912
  u16* vtb = qkv + 12582912;
  u16* mha = qkv;                       // alias: qkv dead after attn
  u16* h1 = e;                          // alias: e dead after W0-gemm

  cast_f32_bf16<<<2048, 256, 0, stream>>>(x, xb, 4096 * 512);
  transpose_weights<<<dim3(16, 16, 7), 256, 0, stream>>>(
      We, Wq, Wk, Wv, W0, W1, W2, Wet, qkvWt, W0t, W1t, W2t);
  biascat<<<12, 256, 0, stream>>>(bq, bk, bv, biasqkv);

  // e = x @ We + be
  gemm_mfma<<<dim3(16, 32), 256, 0, stream>>>(xb, Wet, be, nullptr, e, 4096,
                                              1024, 512, 0, 0);
  // qkv = e @ [Wq|Wk|Wv] + [bq|bk|bv]
  gemm_mfma<<<dim3(48, 32), 256, 0, stream>>>(e, qkvWt, biasqkv, nullptr, qkv,
                                              4096, 3072, 1024, 0, 0);
  transpose_v<<<dim3(32, 32), 256, 0, stream>>>(qkv, vtb);
  attn_kernel<<<dim3(16, 16, 2), 256, 0, stream>>>(qkv, vtb, ctx);
  // mha = e + ctx @ W0 + b0
  gemm_mfma<<<dim3(16, 32), 256, 0, stream>>>(ctx, W0t, b0, e, mha, 4096, 1024,
                                              1024, 0, 0);
  // h1 = relu(mha @ W1 + b1)
  gemm_mfma<<<dim3(16, 32), 256, 0, stream>>>(mha, W1t, b1, nullptr, h1, 4096,
                                              1024, 1024, 1, 0);
  // out = mha + h1 @ W2 + b2 (f32)
  gemm_mfma<<<dim3(16, 32), 256, 0, stream>>>(h1, W2t, b2, mha, d_out, 4096,
                                              1024, 1024, 0, 1);
}